// Round 22
// baseline (316.377 us; speedup 1.0000x reference)
//
#include <hip/hip_runtime.h>
#include <math.h>

#define H 64
#define NODE_IN 128
#define EDGE_IN 16
#define N_NODES 40000
#define N_EDGES 80000
#define N_GRAPHS 256
#define READOUT 1024
#define D2 128   // 2H
#define QS 256   // 4H

typedef unsigned short u16;
typedef __attribute__((ext_vector_type(8))) short bf16x8;
typedef __attribute__((ext_vector_type(4))) float f32x4;
#define MFMA16(a,b,c) __builtin_amdgcn_mfma_f32_16x16x32_bf16(a,b,c,0,0,0)

// device globals
__device__ u16 d_xhi[N_NODES*H];
__device__ u16 d_xlo[N_NODES*H];
__device__ u16 d_efh[N_EDGES*EDGE_IN];   // bf16 edge feats
__device__ u16 d_weF[17*4*2*64*8];       // edge weights, MFMA fragment order
__device__ u16 d_bcF[4*16*64*8];         // gru weights, fragment order
__device__ float d_wspT[256*1024];       // transposed readout weights

__device__ __forceinline__ float sigmoidf_(float x){ return 1.0f/(1.0f + expf(-x)); }

__device__ __forceinline__ u16 bf_hi(float x){
  union { float f; unsigned u; } c; c.f = x;
  unsigned r = (c.u + 0x7FFFu + ((c.u >> 16) & 1u)) >> 16;
  return (u16)r;
}
__device__ __forceinline__ float bf_f(u16 h){
  union { unsigned u; float f; } c; c.u = ((unsigned)h) << 16; return c.f;
}
__device__ __forceinline__ u16 bf_lo(float x, u16 hi){ return bf_hi(x - bf_f(hi)); }

__device__ __forceinline__ bf16x8 rne8(const float* Z){
  union { bf16x8 v; u16 u[8]; } hh;
  #pragma unroll
  for (int k = 0; k < 8; ++k) hh.u[k] = bf_hi(Z[k]);
  return hh.v;
}

// ==================== mega pack: all weight packs + state zero, ONE launch ====
// grid 7320: [0,5000) efh | [5000,6024) wspT | [6024,6792) Bl2 (DEDICATED ws) |
// [6792,7064) weF | [7064,7192) bcF | [7192,7320) zero qstar/hl/cl
__global__ __launch_bounds__(256) void mega_pack(
    const float* __restrict__ We, const float* __restrict__ be,
    const float* __restrict__ gWih, const float* __restrict__ gWhh,
    const float* __restrict__ lWih, const float* __restrict__ lWhh,
    const float* __restrict__ Wsp, const float* __restrict__ ef,
    float* __restrict__ Bl2, float* __restrict__ qzero){
  int b = blockIdx.x, t = threadIdx.x;
  if (b < 5000){
    int i = b*256 + t;                       // 1,280,000
    d_efh[i] = bf_hi(ef[i]);
  } else if (b < 6024){
    int i = (b-5000)*256 + t;                // 262,144
    int j = i >> 8, k = i & 255;
    d_wspT[(size_t)k*1024 + j] = Wsp[i];
  } else if (b < 6792){
    int i = (b-6024)*256 + t;                // 196,608
    int k = i >> 9, c = i & 511;
    int d = c >> 2, gate = c & 3;
    int row = gate*128 + d;
    Bl2[i] = (k < 256) ? lWih[(size_t)row*QS + k] : lWhh[(size_t)row*D2 + (k-256)];
  } else if (b < 7064){
    int i = (b-6792)*256 + t;                // 69,632
    int j = i & 7, lane = (i >> 3) & 63, half = (i >> 9) & 1;
    int nt = (i >> 10) & 3, ci = i >> 12;
    int o = nt*16 + (lane & 15);
    int c = ci*64 + half*32 + (lane >> 4)*8 + j;
    float v = (c < 1024) ? We[(size_t)((c >> 4)*64 + o)*EDGE_IN + (c & 15)]
                         : be[(size_t)(c - 1024)*64 + o];
    d_weF[i] = bf_hi(v);
  } else if (b < 7192){
    int i = (b-7064)*256 + t;                // 32,768
    int j = i & 7, lane = (i >> 3) & 63, nt = (i >> 9) & 15, kc = i >> 13;
    int cr = nt*16 + (lane & 15);
    int k  = kc*32 + (lane >> 4)*8 + j;
    float v;
    if (cr < 128){
      v = (k < 64) ? gWih[(size_t)cr*H + k] : gWhh[(size_t)cr*H + (k-64)];
    } else if (cr < 192){
      int d = cr - 128;
      v = (k < 64) ? gWih[(size_t)(128+d)*H + k] : 0.f;
    } else {
      int d = cr - 192;
      v = (k < 64) ? 0.f : gWhh[(size_t)(128+d)*H + (k-64)];
    }
    d_bcF[i] = bf_hi(v);
  } else {
    int i = (b-7192)*256 + t;                // 32,768 float4 = 131,072 floats
    ((float4*)qzero)[i] = make_float4(0.f,0.f,0.f,0.f);
  }
}

// ==================== proj GEMM (+ fused agg zero for blocks >= 625) ====
__global__ __launch_bounds__(256) void proj_mm(
    const float* __restrict__ nf, const float* __restrict__ Wp,
    const float* __restrict__ bp, float* __restrict__ x0, float* __restrict__ h,
    float* __restrict__ aggz){
  __shared__ float A_s[NODE_IN][64];
  __shared__ float B_s[NODE_IN][64];
  int t = threadIdx.x;
  if (blockIdx.x >= N_NODES/64){
    int bb = blockIdx.x - N_NODES/64;        // 625 zero blocks
    float4* p = (float4*)aggz;
    int i0 = (bb*256 + t)*4;
    #pragma unroll
    for (int j = 0; j < 4; ++j) p[i0 + j] = make_float4(0.f,0.f,0.f,0.f);
    return;
  }
  int nb = blockIdx.x * 64;
  #pragma unroll
  for (int p = 0; p < 8; ++p){
    int idx = p*256 + t;
    int n = idx >> 5, k4 = idx & 31;
    float4 v = ((const float4*)(nf + (size_t)(nb+n)*NODE_IN))[k4];
    int base = (((n>>2) ^ (k4 & 15)) << 2) + (n & 3);
    A_s[k4*4+0][base]=v.x; A_s[k4*4+1][base]=v.y;
    A_s[k4*4+2][base]=v.z; A_s[k4*4+3][base]=v.w;
  }
  #pragma unroll
  for (int p = 0; p < 8; ++p){
    int idx = p*256 + t;
    int c = idx & 63, k4 = idx >> 6;
    float4 v = ((const float4*)(Wp + (size_t)c*NODE_IN))[k4];
    B_s[k4*4+0][c]=v.x; B_s[k4*4+1][c]=v.y; B_s[k4*4+2][c]=v.z; B_s[k4*4+3][c]=v.w;
  }
  __syncthreads();
  int eg = t & 15, cg = t >> 4;
  float acc[4][4] = {};
  #pragma unroll 4
  for (int k = 0; k < NODE_IN; ++k){
    int s = (k >> 2) & 15;
    float4 a = *(const float4*)&A_s[k][(eg ^ s) << 2];
    float4 b = *(const float4*)&B_s[k][cg*4];
    float av[4] = {a.x,a.y,a.z,a.w};
    float bv[4] = {b.x,b.y,b.z,b.w};
    #pragma unroll
    for (int j = 0; j < 4; ++j)
      #pragma unroll
      for (int c = 0; c < 4; ++c) acc[j][c] += av[j]*bv[c];
  }
  float4 bb = ((const float4*)bp)[cg];
  float bv[4] = {bb.x,bb.y,bb.z,bb.w};
  #pragma unroll
  for (int j = 0; j < 4; ++j){
    int n = nb + eg*4 + j;
    float o[4];
    #pragma unroll
    for (int c = 0; c < 4; ++c) o[c] = fmaxf(acc[j][c]+bv[c], 0.f);
    *(float4*)(x0 + (size_t)n*H + cg*4) = make_float4(o[0],o[1],o[2],o[3]);
    *(float4*)(h  + (size_t)n*H + cg*4) = make_float4(o[0],o[1],o[2],o[3]);
    u16 hs[4], ls[4];
    #pragma unroll
    for (int c = 0; c < 4; ++c){ hs[c] = bf_hi(o[c]); ls[c] = bf_lo(o[c], hs[c]); }
    *(ushort4*)&d_xhi[(size_t)n*H + cg*4] = make_ushort4(hs[0],hs[1],hs[2],hs[3]);
    *(ushort4*)&d_xlo[(size_t)n*H + cg*4] = make_ushort4(ls[0],ls[1],ls[2],ls[3]);
  }
}

// ==================== fused edge message: barrier-free, bf16 inputs ====
__global__ __launch_bounds__(256) void edge_mfma(
    const int* __restrict__ src, const int* __restrict__ dst,
    float* __restrict__ agg){
  __shared__ __align__(16) float x_s[64][68];
  int t = threadIdx.x;
  int w = t >> 6, lane = t & 63;
  int m = lane & 15, kq = lane >> 4;
  int ebase = blockIdx.x * 64;
  int e0 = t >> 2, j4 = t & 3;
  {
    int s0 = src[ebase + e0];
    const bf16x8* ph = (const bf16x8*)&d_xhi[(size_t)s0*H + j4*16];
    union { bf16x8 v; u16 u[8]; } a, b;
    a.v = ph[0]; b.v = ph[1];
    float* xr = &x_s[e0][j4*16];
    #pragma unroll
    for (int j = 0; j < 8; ++j){
      xr[j]     = bf_f(a.u[j]);
      xr[8 + j] = bf_f(b.u[j]);
    }
  }
  int e = w*16 + m;
  float ef8[8];
  {
    const bf16x8* p = (const bf16x8*)&d_efh[(size_t)(ebase+e)*EDGE_IN + (kq&1)*8];
    union { bf16x8 v; u16 u[8]; } t8; t8.v = p[0];
    #pragma unroll
    for (int j = 0; j < 8; ++j) ef8[j] = bf_f(t8.u[j]);
  }
  int hsel = kq >> 1;
  const bf16x8* wF = (const bf16x8*)d_weF + lane;
  f32x4 acc[4];
  #pragma unroll
  for (int i = 0; i < 4; ++i) acc[i] = (f32x4){0.f,0.f,0.f,0.f};

  #pragma unroll 2
  for (int ci = 0; ci < 16; ++ci){
    float x0v = x_s[e][ci*4 + hsel];
    float x1v = x_s[e][ci*4 + 2 + hsel];
    float Z0[8], Z1[8];
    #pragma unroll
    for (int j = 0; j < 8; ++j){ Z0[j] = x0v*ef8[j]; Z1[j] = x1v*ef8[j]; }
    bf16x8 a0 = rne8(Z0), a1 = rne8(Z1);
    #pragma unroll
    for (int nt = 0; nt < 4; ++nt){
      bf16x8 b0 = wF[(size_t)((ci*4+nt)*2 + 0)*64];
      bf16x8 b1 = wF[(size_t)((ci*4+nt)*2 + 1)*64];
      acc[nt] = MFMA16(a0, b0, acc[nt]);
      acc[nt] = MFMA16(a1, b1, acc[nt]);
    }
  }
  {
    float xb[16];
    {
      const float4* q0 = (const float4*)&x_s[e][kq*8];
      const float4* q1 = (const float4*)&x_s[e][32 + kq*8];
      float4 a=q0[0], b=q0[1], c=q1[0], d=q1[1];
      xb[0]=a.x; xb[1]=a.y; xb[2]=a.z; xb[3]=a.w;
      xb[4]=b.x; xb[5]=b.y; xb[6]=b.z; xb[7]=b.w;
      xb[8]=c.x; xb[9]=c.y; xb[10]=c.z; xb[11]=c.w;
      xb[12]=d.x; xb[13]=d.y; xb[14]=d.z; xb[15]=d.w;
    }
    bf16x8 a0 = rne8(xb), a1 = rne8(xb + 8);
    #pragma unroll
    for (int nt = 0; nt < 4; ++nt){
      bf16x8 b0 = wF[(size_t)((64+nt)*2 + 0)*64];
      bf16x8 b1 = wF[(size_t)((64+nt)*2 + 1)*64];
      acc[nt] = MFMA16(a0, b0, acc[nt]);
      acc[nt] = MFMA16(a1, b1, acc[nt]);
    }
  }
  float* msg_s = (float*)x_s;
  #pragma unroll
  for (int nt = 0; nt < 4; ++nt){
    int o = nt*16 + m;
    #pragma unroll
    for (int r = 0; r < 4; ++r){
      int ee = w*16 + kq*4 + r;
      msg_s[ee*68 + (o ^ ((ee & 7) << 2))] = acc[nt][r];
    }
  }
  #pragma unroll
  for (int r = 0; r < 16; ++r){
    int ee = w*16 + r;
    int dn = dst[ebase + ee];
    atomicAdd(&agg[(size_t)dn*H + lane],
              msg_s[ee*68 + (lane ^ ((ee & 7) << 2))]);
  }
}

// ==================== GRU GEMM + fused epilogue; B from L2 fragments ====
__global__ __launch_bounds__(256) void gru_mm_mfma(
    float* __restrict__ agg, const float* __restrict__ bconv,
    float* __restrict__ h, const float* __restrict__ gbih,
    const float* __restrict__ gbhh){
  __shared__ u16 Ah[64][40], Al[64][40];
  __shared__ float bih_s[192], bhh_s[192];
  int t = threadIdx.x;
  int w = t >> 6, lane = t & 63;
  int nb = blockIdx.x * 64;
  if (t < 192){ bih_s[t] = gbih[t]; bhh_s[t] = gbhh[t]; }
  int m = lane & 15, kj = (lane >> 4) * 8;
  const bf16x8* bF = (const bf16x8*)d_bcF + lane;
  f32x4 acc[16];
  #pragma unroll
  for (int i = 0; i < 16; ++i) acc[i] = (f32x4){0.f,0.f,0.f,0.f};
  for (int kc = 0; kc < 4; ++kc){
    {
      int n = t >> 2, q = t & 3;
      if (kc < 2){
        float* sp = agg + (size_t)(nb+n)*H + kc*32 + q*8;
        float4 v0 = *(const float4*)sp;
        float4 v1 = *(const float4*)(sp + 4);
        float4 b0 = *(const float4*)&bconv[kc*32 + q*8];
        float4 b1 = *(const float4*)&bconv[kc*32 + q*8 + 4];
        *(float4*)sp       = make_float4(0.f,0.f,0.f,0.f);
        *(float4*)(sp + 4) = make_float4(0.f,0.f,0.f,0.f);
        float vals[8] = { fmaxf(v0.x+b0.x,0.f), fmaxf(v0.y+b0.y,0.f),
                          fmaxf(v0.z+b0.z,0.f), fmaxf(v0.w+b0.w,0.f),
                          fmaxf(v1.x+b1.x,0.f), fmaxf(v1.y+b1.y,0.f),
                          fmaxf(v1.z+b1.z,0.f), fmaxf(v1.w+b1.w,0.f) };
        union { bf16x8 v; u16 u[8]; } ph, pl;
        #pragma unroll
        for (int j = 0; j < 8; ++j){
          u16 hi = bf_hi(vals[j]);
          ph.u[j] = hi; pl.u[j] = bf_lo(vals[j], hi);
        }
        *(bf16x8*)&Ah[n][q*8] = ph.v;
        *(bf16x8*)&Al[n][q*8] = pl.v;
      } else {
        int gofs = (nb+n)*H + (kc-2)*32 + q*8;
        *(bf16x8*)&Ah[n][q*8] = *(const bf16x8*)&d_xhi[gofs];
        *(bf16x8*)&Al[n][q*8] = *(const bf16x8*)&d_xlo[gofs];
      }
    }
    bf16x8 ah = *(const bf16x8*)&Ah[w*16 + m][kj];
    bf16x8 al = *(const bf16x8*)&Al[w*16 + m][kj];
    #pragma unroll
    for (int nt = 0; nt < 16; ++nt){
      bf16x8 bh = bF[(size_t)(kc*16 + nt)*64];
      acc[nt] = MFMA16(ah, bh, acc[nt]);
      acc[nt] = MFMA16(al, bh, acc[nt]);
    }
  }
  __syncthreads();
  int q4 = lane >> 4, col0 = lane & 15;
  #pragma unroll
  for (int r = 0; r < 4; ++r){
    int node = nb + w*16 + q4*4 + r;
    #pragma unroll
    for (int j = 0; j < 4; ++j){
      int d = col0 + 16*j;
      float rg = sigmoidf_(acc[j][r]   + bih_s[d]      + bhh_s[d]);
      float z  = sigmoidf_(acc[4+j][r] + bih_s[64+d]   + bhh_s[64+d]);
      float nn = tanhf(acc[8+j][r] + bih_s[128+d] + rg*(acc[12+j][r] + bhh_s[128+d]));
      size_t off = (size_t)node*H + d;
      float hv = h[off];
      float hn = (1.f - z)*nn + z*hv;
      h[off] = hn;
      u16 hb = bf_hi(hn);
      d_xhi[off] = hb;
      d_xlo[off] = bf_lo(hn, hb);
    }
  }
}

// ==================== fused Set2Set step: LSTM + attention (+ readout on last) ====
__global__ __launch_bounds__(512) void s2s_kernel(
    const float* __restrict__ x0, const float* __restrict__ h,
    const float* __restrict__ Bl2, const float* __restrict__ lbih,
    const float* __restrict__ lbhh, float* __restrict__ hl,
    float* __restrict__ cl, float* __restrict__ qstar,
    const float* __restrict__ bsp, const float* __restrict__ prelu,
    float* __restrict__ outp, int doOut){
  __shared__ float A_s[384];
  __shared__ float part4[4][128][4];
  __shared__ float q_s[D2];
  __shared__ float alpha_s[160];
  __shared__ float wred[8];
  __shared__ float part[8][D2];
  int g = blockIdx.x, t = threadIdx.x;
  int lane = t & 63, w = t >> 6;
  if (t < 384){
    A_s[t] = (t < 256) ? qstar[(size_t)g*QS + t] : hl[(size_t)g*D2 + (t - 256)];
  }
  __syncthreads();
  {
    int d = t & 127, ks = t >> 7;
    const float* bp = Bl2 + 4*d;
    float ai = 0.f, af = 0.f, ag = 0.f, ao = 0.f;
    #pragma unroll 8
    for (int kk = 0; kk < 96; ++kk){
      int k = ks*96 + kk;
      float a = A_s[k];
      float4 b = *(const float4*)(bp + (size_t)k*512);
      ai += a*b.x; af += a*b.y; ag += a*b.z; ao += a*b.w;
    }
    *(float4*)&part4[ks][d][0] = make_float4(ai, af, ag, ao);
  }
  __syncthreads();
  if (t < D2){
    float4 p0 = *(const float4*)&part4[0][t][0];
    float4 p1 = *(const float4*)&part4[1][t][0];
    float4 p2 = *(const float4*)&part4[2][t][0];
    float4 p3 = *(const float4*)&part4[3][t][0];
    float iv = p0.x+p1.x+p2.x+p3.x + lbih[t]       + lbhh[t];
    float fv = p0.y+p1.y+p2.y+p3.y + lbih[128 + t] + lbhh[128 + t];
    float gv = p0.z+p1.z+p2.z+p3.z + lbih[256 + t] + lbhh[256 + t];
    float ov = p0.w+p1.w+p2.w+p3.w + lbih[384 + t] + lbhh[384 + t];
    float c = sigmoidf_(fv)*cl[(size_t)g*D2 + t] + sigmoidf_(iv)*tanhf(gv);
    float hn = sigmoidf_(ov)*tanhf(c);
    cl[(size_t)g*D2 + t] = c;
    hl[(size_t)g*D2 + t] = hn;
    q_s[t] = hn;
  }
  __syncthreads();
  int n0 = (g*N_NODES + N_GRAPHS - 1)/N_GRAPHS;
  int n1 = ((g+1)*N_NODES + N_GRAPHS - 1)/N_GRAPHS;
  int cnt = n1 - n0;
  float e = -1e30f;
  if (t < cnt){
    int n = n0 + t;
    const float4* xr = (const float4*)(x0 + (size_t)n*H);
    const float4* hr = (const float4*)(h  + (size_t)n*H);
    const float4* q1 = (const float4*)q_s;
    const float4* q2 = (const float4*)(q_s + H);
    float s = 0.0f;
    #pragma unroll
    for (int k4 = 0; k4 < 16; ++k4){
      float4 a = xr[k4], b = q1[k4];
      s += a.x*b.x + a.y*b.y + a.z*b.z + a.w*b.w;
    }
    #pragma unroll
    for (int k4 = 0; k4 < 16; ++k4){
      float4 a = hr[k4], b = q2[k4];
      s += a.x*b.x + a.y*b.y + a.z*b.z + a.w*b.w;
    }
    e = s;
  }
  float mx = e;
  #pragma unroll
  for (int off = 32; off >= 1; off >>= 1) mx = fmaxf(mx, __shfl_xor(mx, off));
  if (lane == 0) wred[w] = mx;
  __syncthreads();
  float gm = wred[0];
  #pragma unroll
  for (int i = 1; i < 8; ++i) gm = fmaxf(gm, wred[i]);
  __syncthreads();
  float ex = (t < cnt) ? expf(e - gm) : 0.0f;
  float sm = ex;
  #pragma unroll
  for (int off = 32; off >= 1; off >>= 1) sm += __shfl_xor(sm, off);
  if (lane == 0) wred[w] = sm;
  __syncthreads();
  float denom = wred[0]+wred[1]+wred[2]+wred[3]+wred[4]+wred[5]+wred[6]+wred[7];
  if (t < cnt) alpha_s[t] = ex / denom;
  __syncthreads();
  float acc0 = 0.f, acc1 = 0.f;
  for (int i = w; i < cnt; i += 8){
    float a = alpha_s[i];
    acc0 += a * x0[(size_t)(n0+i)*H + lane];
    acc1 += a * h [(size_t)(n0+i)*H + lane];
  }
  part[w][lane]      = acc0;
  part[w][64 + lane] = acc1;
  __syncthreads();
  if (t < D2){
    float v = 0.f;
    #pragma unroll
    for (int i = 0; i < 8; ++i) v += part[i][t];
    qstar[(size_t)g*QS + t]      = q_s[t];
    qstar[(size_t)g*QS + D2 + t] = v;
    if (doOut){ A_s[t] = q_s[t]; A_s[D2 + t] = v; }
  }
  if (doOut){
    __syncthreads();
    float pw = prelu[0];
    #pragma unroll
    for (int rep = 0; rep < 2; ++rep){
      int j = rep*512 + t;
      float acc = bsp[j];
      #pragma unroll 4
      for (int k = 0; k < QS; ++k)
        acc += A_s[k] * d_wspT[(size_t)k*1024 + j];
      outp[(size_t)g*READOUT + j] = (acc >= 0.0f) ? acc : pw*acc;
    }
  }
}

extern "C" void kernel_launch(void* const* d_in, const int* in_sizes, int n_in,
                              void* d_out, int out_size, void* d_ws, size_t ws_size,
                              hipStream_t stream) {
  const float* node_feats = (const float*)d_in[0];
  const float* edge_feats = (const float*)d_in[1];
  const int*   esrc       = (const int*)d_in[2];
  const int*   edst       = (const int*)d_in[3];
  const float* Wproj = (const float*)d_in[5];
  const float* bproj = (const float*)d_in[6];
  const float* Wedge = (const float*)d_in[7];
  const float* bedge = (const float*)d_in[8];
  const float* bconv = (const float*)d_in[9];
  const float* gWih  = (const float*)d_in[10];
  const float* gWhh  = (const float*)d_in[11];
  const float* gbih  = (const float*)d_in[12];
  const float* gbhh  = (const float*)d_in[13];
  const float* lWih  = (const float*)d_in[14];
  const float* lWhh  = (const float*)d_in[15];
  const float* lbih  = (const float*)d_in[16];
  const float* lbhh  = (const float*)d_in[17];
  const float* Wsp   = (const float*)d_in[18];
  const float* bsp   = (const float*)d_in[19];
  const float* prelu = (const float*)d_in[20];

  float* ws    = (float*)d_ws;
  float* x0    = ws;                     // 2,560,000
  float* h     = ws + 2560000;           // 2,560,000
  float* agg   = ws + 5120000;           // 2,560,000
  float* qstar = ws + 7680000;           // 65,536
  float* hl    = qstar + 65536;          // 32,768
  float* cl    = hl + 32768;             // 32,768
  float* Bl2   = cl + 32768;             // 196,608 DEDICATED (no agg alias!)
                                         // total 8,007,680 floats = 32 MB

  // one launch: all packs + Bl2 + zero qstar/hl/cl
  mega_pack<<<7320, 256, 0, stream>>>(Wedge, bedge, gWih, gWhh, lWih, lWhh,
                                      Wsp, edge_feats, Bl2, qstar);

  // proj + fused agg zero
  proj_mm<<<2*(N_NODES/64), 256, 0, stream>>>(node_feats, Wproj, bproj, x0, h, agg);

  for (int s = 0; s < 3; ++s){
    edge_mfma<<<N_EDGES/64, 256, 0, stream>>>(esrc, edst, agg);
    gru_mm_mfma<<<N_NODES/64, 256, 0, stream>>>(agg, bconv, h, gbih, gbhh);  // zeroes agg
  }

  for (int s = 0; s < 3; ++s){
    s2s_kernel<<<N_GRAPHS, 512, 0, stream>>>(x0, h, Bl2, lbih, lbhh, hl, cl,
                                             qstar, bsp, prelu, (float*)d_out,
                                             s == 2 ? 1 : 0);
  }
}

// Round 23
// 313.451 us; speedup vs baseline: 1.0093x; 1.0093x over previous
//
#include <hip/hip_runtime.h>
#include <math.h>

#define H 64
#define NODE_IN 128
#define EDGE_IN 16
#define N_NODES 40000
#define N_EDGES 80000
#define N_GRAPHS 256
#define READOUT 1024
#define D2 128   // 2H
#define QS 256   // 4H

typedef unsigned short u16;
typedef __attribute__((ext_vector_type(8))) short bf16x8;
typedef __attribute__((ext_vector_type(4))) float f32x4;
#define MFMA16(a,b,c) __builtin_amdgcn_mfma_f32_16x16x32_bf16(a,b,c,0,0,0)

// device globals
__device__ u16 d_xhi[N_NODES*H];
__device__ u16 d_xlo[N_NODES*H];
// edge weights in MFMA FRAGMENT order: [((ci*4+nt)*2+half)*64+lane] x bf16x8
__device__ u16 d_weF[17*4*2*64*8];
// gru weights in fragment order: [(kc*16+nt)*64+lane] x bf16x8
__device__ u16 d_bcF[4*16*64*8];
__device__ float d_wspT[256*1024];

__device__ __forceinline__ float sigmoidf_(float x){ return 1.0f/(1.0f + expf(-x)); }

__device__ __forceinline__ u16 bf_hi(float x){
  union { float f; unsigned u; } c; c.f = x;
  unsigned r = (c.u + 0x7FFFu + ((c.u >> 16) & 1u)) >> 16;
  return (u16)r;
}
__device__ __forceinline__ float bf_f(u16 h){
  union { unsigned u; float f; } c; c.u = ((unsigned)h) << 16; return c.f;
}
__device__ __forceinline__ u16 bf_lo(float x, u16 hi){ return bf_hi(x - bf_f(hi)); }

// RNE-round 8 f32 -> bf16x8
__device__ __forceinline__ bf16x8 rne8(const float* Z){
  union { bf16x8 v; u16 u[8]; } hh;
  #pragma unroll
  for (int k = 0; k < 8; ++k) hh.u[k] = bf_hi(Z[k]);
  return hh.v;
}

// ==================== weight packs (once per launch) ====================
// edge weights -> fragment order. c = ci*64 + half*32 + kq*8 + j
__global__ __launch_bounds__(256) void pack_weF(
    const float* __restrict__ We, const float* __restrict__ be){
  int i = blockIdx.x*256 + threadIdx.x;     // 69632
  int j = i & 7, lane = (i >> 3) & 63, half = (i >> 9) & 1;
  int nt = (i >> 10) & 3, ci = i >> 12;
  int o = nt*16 + (lane & 15);
  int c = ci*64 + half*32 + (lane >> 4)*8 + j;
  float v = (c < 1024) ? We[(size_t)((c >> 4)*64 + o)*EDGE_IN + (c & 15)]
                       : be[(size_t)(c - 1024)*64 + o];
  d_weF[i] = bf_hi(v);
}

// gru weights -> fragment order. row c_row = nt*16+(lane&15), k = kc*32+(lane>>4)*8+j
__global__ __launch_bounds__(256) void pack_bcF(
    const float* __restrict__ Wih, const float* __restrict__ Whh){
  int i = blockIdx.x*256 + threadIdx.x;     // 32768
  int j = i & 7, lane = (i >> 3) & 63, nt = (i >> 9) & 15, kc = i >> 13;
  int cr = nt*16 + (lane & 15);
  int k  = kc*32 + (lane >> 4)*8 + j;
  float v;
  if (cr < 128){
    v = (k < 64) ? Wih[(size_t)cr*H + k] : Whh[(size_t)cr*H + (k-64)];
  } else if (cr < 192){
    int d = cr - 128;
    v = (k < 64) ? Wih[(size_t)(128+d)*H + k] : 0.f;
  } else {
    int d = cr - 192;
    v = (k < 64) ? 0.f : Whh[(size_t)(128+d)*H + (k-64)];
  }
  d_bcF[i] = bf_hi(v);
}

__global__ __launch_bounds__(256) void pack_wspT(const float* __restrict__ Wsp){
  int i = blockIdx.x*256 + threadIdx.x;     // 262144
  int j = i >> 8, k = i & 255;
  d_wspT[(size_t)k*1024 + j] = Wsp[i];
}

// ==================== zero fill ====================
__global__ __launch_bounds__(256) void zero_buf(float4* __restrict__ p, int n4){
  int i = blockIdx.x*256 + threadIdx.x;
  int stride = gridDim.x*256;
  for (; i < n4; i += stride) p[i] = make_float4(0.f,0.f,0.f,0.f);
}

// ==================== proj GEMM ====================
__global__ __launch_bounds__(256) void proj_mm(
    const float* __restrict__ nf, const float* __restrict__ Wp,
    const float* __restrict__ bp, float* __restrict__ x0, float* __restrict__ h){
  __shared__ float A_s[NODE_IN][64];
  __shared__ float B_s[NODE_IN][64];
  int t = threadIdx.x;
  int nb = blockIdx.x * 64;
  #pragma unroll
  for (int p = 0; p < 8; ++p){
    int idx = p*256 + t;
    int n = idx >> 5, k4 = idx & 31;
    float4 v = ((const float4*)(nf + (size_t)(nb+n)*NODE_IN))[k4];
    int base = (((n>>2) ^ (k4 & 15)) << 2) + (n & 3);
    A_s[k4*4+0][base]=v.x; A_s[k4*4+1][base]=v.y;
    A_s[k4*4+2][base]=v.z; A_s[k4*4+3][base]=v.w;
  }
  #pragma unroll
  for (int p = 0; p < 8; ++p){
    int idx = p*256 + t;
    int c = idx & 63, k4 = idx >> 6;
    float4 v = ((const float4*)(Wp + (size_t)c*NODE_IN))[k4];
    B_s[k4*4+0][c]=v.x; B_s[k4*4+1][c]=v.y; B_s[k4*4+2][c]=v.z; B_s[k4*4+3][c]=v.w;
  }
  __syncthreads();
  int eg = t & 15, cg = t >> 4;
  float acc[4][4] = {};
  #pragma unroll 4
  for (int k = 0; k < NODE_IN; ++k){
    int s = (k >> 2) & 15;
    float4 a = *(const float4*)&A_s[k][(eg ^ s) << 2];
    float4 b = *(const float4*)&B_s[k][cg*4];
    float av[4] = {a.x,a.y,a.z,a.w};
    float bv[4] = {b.x,b.y,b.z,b.w};
    #pragma unroll
    for (int j = 0; j < 4; ++j)
      #pragma unroll
      for (int c = 0; c < 4; ++c) acc[j][c] += av[j]*bv[c];
  }
  float4 bb = ((const float4*)bp)[cg];
  float bv[4] = {bb.x,bb.y,bb.z,bb.w};
  #pragma unroll
  for (int j = 0; j < 4; ++j){
    int n = nb + eg*4 + j;
    float o[4];
    #pragma unroll
    for (int c = 0; c < 4; ++c) o[c] = fmaxf(acc[j][c]+bv[c], 0.f);
    *(float4*)(x0 + (size_t)n*H + cg*4) = make_float4(o[0],o[1],o[2],o[3]);
    *(float4*)(h  + (size_t)n*H + cg*4) = make_float4(o[0],o[1],o[2],o[3]);
    u16 hs[4], ls[4];
    #pragma unroll
    for (int c = 0; c < 4; ++c){ hs[c] = bf_hi(o[c]); ls[c] = bf_lo(o[c], hs[c]); }
    *(ushort4*)&d_xhi[(size_t)n*H + cg*4] = make_ushort4(hs[0],hs[1],hs[2],hs[3]);
    *(ushort4*)&d_xlo[(size_t)n*H + cg*4] = make_ushort4(ls[0],ls[1],ls[2],ls[3]);
  }
}

// ==================== fused edge message: BARRIER-FREE ====
// B fragments loaded coalesced from L2 (fragment-packed d_weF); x_s rows,
// ef, msg rows, flush all wave-private (wave w owns edges w*16..w*16+15)
// -> zero __syncthreads; waves fully independent. LDS 17.4 KB -> 8 blocks/CU.
__global__ __launch_bounds__(256) void edge_mfma(
    const float* __restrict__ xf, const float* __restrict__ ef,
    const int* __restrict__ src, const int* __restrict__ dst,
    float* __restrict__ agg){
  __shared__ __align__(16) float x_s[64][68];   // msg overlay (stride 68, wave-private)
  int t = threadIdx.x;
  int w = t >> 6, lane = t & 63;
  int m = lane & 15, kq = lane >> 4;
  int ebase = blockIdx.x * 64;
  int e0 = t >> 2, j4 = t & 3;     // e0 in [w*16, w*16+16): own-wave rows
  { // stage own x row quarter
    int s0 = src[ebase + e0];
    const float4* px = (const float4*)(xf + (size_t)s0*H + j4*16);
    float4 v0=px[0], v1=px[1], v2=px[2], v3=px[3];
    float* xr = &x_s[e0][j4*16];
    *(float4*)xr      = v0;
    *(float4*)(xr+4)  = v1;
    *(float4*)(xr+8)  = v2;
    *(float4*)(xr+12) = v3;
  }
  int e = w*16 + m;
  float ef8[8];
  {
    const float4* p = (const float4*)(ef + (size_t)(ebase+e)*EDGE_IN + (kq&1)*8);
    float4 a = p[0], b = p[1];
    ef8[0]=a.x; ef8[1]=a.y; ef8[2]=a.z; ef8[3]=a.w;
    ef8[4]=b.x; ef8[5]=b.y; ef8[6]=b.z; ef8[7]=b.w;
  }
  int hsel = kq >> 1;
  const bf16x8* wF = (const bf16x8*)d_weF + lane;   // fragment stride 64
  f32x4 acc[4];
  #pragma unroll
  for (int i = 0; i < 4; ++i) acc[i] = (f32x4){0.f,0.f,0.f,0.f};

  #pragma unroll 2
  for (int ci = 0; ci < 16; ++ci){
    float x0v = x_s[e][ci*4 + hsel];
    float x1v = x_s[e][ci*4 + 2 + hsel];
    float Z0[8], Z1[8];
    #pragma unroll
    for (int j = 0; j < 8; ++j){ Z0[j] = x0v*ef8[j]; Z1[j] = x1v*ef8[j]; }
    bf16x8 a0 = rne8(Z0), a1 = rne8(Z1);
    #pragma unroll
    for (int nt = 0; nt < 4; ++nt){
      bf16x8 b0 = wF[(size_t)((ci*4+nt)*2 + 0)*64];
      bf16x8 b1 = wF[(size_t)((ci*4+nt)*2 + 1)*64];
      acc[nt] = MFMA16(a0, b0, acc[nt]);
      acc[nt] = MFMA16(a1, b1, acc[nt]);
    }
  }
  { // bias chunk (ci = 16)
    float xb[16];
    {
      const float4* q0 = (const float4*)&x_s[e][kq*8];
      const float4* q1 = (const float4*)&x_s[e][32 + kq*8];
      float4 a=q0[0], b=q0[1], c=q1[0], d=q1[1];
      xb[0]=a.x; xb[1]=a.y; xb[2]=a.z; xb[3]=a.w;
      xb[4]=b.x; xb[5]=b.y; xb[6]=b.z; xb[7]=b.w;
      xb[8]=c.x; xb[9]=c.y; xb[10]=c.z; xb[11]=c.w;
      xb[12]=d.x; xb[13]=d.y; xb[14]=d.z; xb[15]=d.w;
    }
    bf16x8 a0 = rne8(xb), a1 = rne8(xb + 8);
    #pragma unroll
    for (int nt = 0; nt < 4; ++nt){
      bf16x8 b0 = wF[(size_t)((64+nt)*2 + 0)*64];
      bf16x8 b1 = wF[(size_t)((64+nt)*2 + 1)*64];
      acc[nt] = MFMA16(a0, b0, acc[nt]);
      acc[nt] = MFMA16(a1, b1, acc[nt]);
    }
  }
  // msg overlay (stride 68 keeps rows wave-private; own-wave LDS is in-order)
  float* msg_s = (float*)x_s;
  #pragma unroll
  for (int nt = 0; nt < 4; ++nt){
    int o = nt*16 + m;
    #pragma unroll
    for (int r = 0; r < 4; ++r){
      int ee = w*16 + kq*4 + r;
      msg_s[ee*68 + (o ^ ((ee & 7) << 2))] = acc[nt][r];
    }
  }
  // coalesced atomic flush (own edges)
  #pragma unroll
  for (int r = 0; r < 16; ++r){
    int ee = w*16 + r;
    int dn = dst[ebase + ee];
    atomicAdd(&agg[(size_t)dn*H + lane],
              msg_s[ee*68 + (lane ^ ((ee & 7) << 2))]);
  }
}

// ==================== GRU GEMM + fused epilogue; B from L2 fragments ====
// A staging wave-private (rows w*16..+15) -> no K-loop barriers; one barrier
// before epilogue for bias LDS. Zeroes agg rows after reading.
__global__ __launch_bounds__(256) void gru_mm_mfma(
    float* __restrict__ agg, const float* __restrict__ bconv,
    float* __restrict__ h, const float* __restrict__ gbih,
    const float* __restrict__ gbhh){
  __shared__ u16 Ah[64][40], Al[64][40];
  __shared__ float bih_s[192], bhh_s[192];
  int t = threadIdx.x;
  int w = t >> 6, lane = t & 63;
  int nb = blockIdx.x * 64;
  if (t < 192){ bih_s[t] = gbih[t]; bhh_s[t] = gbhh[t]; }
  int m = lane & 15, kj = (lane >> 4) * 8;
  const bf16x8* bF = (const bf16x8*)d_bcF + lane;
  f32x4 acc[16];
  #pragma unroll
  for (int i = 0; i < 16; ++i) acc[i] = (f32x4){0.f,0.f,0.f,0.f};
  for (int kc = 0; kc < 4; ++kc){
    { // stage A chunk: rows n = t>>2 are own-wave; in-order within wave
      int n = t >> 2, q = t & 3;
      if (kc < 2){
        float* sp = agg + (size_t)(nb+n)*H + kc*32 + q*8;
        float4 v0 = *(const float4*)sp;
        float4 v1 = *(const float4*)(sp + 4);
        float4 b0 = *(const float4*)&bconv[kc*32 + q*8];
        float4 b1 = *(const float4*)&bconv[kc*32 + q*8 + 4];
        *(float4*)sp       = make_float4(0.f,0.f,0.f,0.f);
        *(float4*)(sp + 4) = make_float4(0.f,0.f,0.f,0.f);
        float vals[8] = { fmaxf(v0.x+b0.x,0.f), fmaxf(v0.y+b0.y,0.f),
                          fmaxf(v0.z+b0.z,0.f), fmaxf(v0.w+b0.w,0.f),
                          fmaxf(v1.x+b1.x,0.f), fmaxf(v1.y+b1.y,0.f),
                          fmaxf(v1.z+b1.z,0.f), fmaxf(v1.w+b1.w,0.f) };
        union { bf16x8 v; u16 u[8]; } ph, pl;
        #pragma unroll
        for (int j = 0; j < 8; ++j){
          u16 hi = bf_hi(vals[j]);
          ph.u[j] = hi; pl.u[j] = bf_lo(vals[j], hi);
        }
        *(bf16x8*)&Ah[n][q*8] = ph.v;
        *(bf16x8*)&Al[n][q*8] = pl.v;
      } else {
        int gofs = (nb+n)*H + (kc-2)*32 + q*8;
        *(bf16x8*)&Ah[n][q*8] = *(const bf16x8*)&d_xhi[gofs];
        *(bf16x8*)&Al[n][q*8] = *(const bf16x8*)&d_xlo[gofs];
      }
    }
    bf16x8 ah = *(const bf16x8*)&Ah[w*16 + m][kj];
    bf16x8 al = *(const bf16x8*)&Al[w*16 + m][kj];
    #pragma unroll
    for (int nt = 0; nt < 16; ++nt){
      bf16x8 bh = bF[(size_t)(kc*16 + nt)*64];
      acc[nt] = MFMA16(ah, bh, acc[nt]);
      acc[nt] = MFMA16(al, bh, acc[nt]);
    }
  }
  __syncthreads();   // bias LDS visible to all waves
  int q4 = lane >> 4, col0 = lane & 15;
  #pragma unroll
  for (int r = 0; r < 4; ++r){
    int node = nb + w*16 + q4*4 + r;
    #pragma unroll
    for (int j = 0; j < 4; ++j){
      int d = col0 + 16*j;
      float rg = sigmoidf_(acc[j][r]   + bih_s[d]      + bhh_s[d]);
      float z  = sigmoidf_(acc[4+j][r] + bih_s[64+d]   + bhh_s[64+d]);
      float nn = tanhf(acc[8+j][r] + bih_s[128+d] + rg*(acc[12+j][r] + bhh_s[128+d]));
      size_t off = (size_t)node*H + d;
      float hv = h[off];
      float hn = (1.f - z)*nn + z*hv;
      h[off] = hn;
      u16 hb = bf_hi(hn);
      d_xhi[off] = hb;
      d_xlo[off] = bf_lo(hn, hb);
    }
  }
}

// ==================== Bl2 pack ====================
__global__ __launch_bounds__(256) void build_bl2(
    const float* __restrict__ Wih, const float* __restrict__ Whh,
    float* __restrict__ Bl2){
  int i = blockIdx.x*256 + threadIdx.x;   // 196608
  int k = i >> 9, c = i & 511;
  int d = c >> 2, gate = c & 3;
  int row = gate*128 + d;
  float v = (k < 256) ? Wih[(size_t)row*QS + k] : Whh[(size_t)row*D2 + (k-256)];
  Bl2[i] = v;
}

// ==================== fused Set2Set step: LSTM cell + attention (512 thr) ====
__global__ __launch_bounds__(512) void s2s_kernel(
    const float* __restrict__ x0, const float* __restrict__ h,
    const float* __restrict__ Bl2, const float* __restrict__ lbih,
    const float* __restrict__ lbhh, float* __restrict__ hl,
    float* __restrict__ cl, float* __restrict__ qstar){
  __shared__ float A_s[384];
  __shared__ float part4[4][128][4];
  __shared__ float q_s[D2];
  __shared__ float alpha_s[160];
  __shared__ float wred[8];
  __shared__ float part[8][D2];
  int g = blockIdx.x, t = threadIdx.x;
  int lane = t & 63, w = t >> 6;
  if (t < 384){
    A_s[t] = (t < 256) ? qstar[(size_t)g*QS + t] : hl[(size_t)g*D2 + (t - 256)];
  }
  __syncthreads();
  {
    int d = t & 127, ks = t >> 7;
    const float* bp = Bl2 + 4*d;
    float ai = 0.f, af = 0.f, ag = 0.f, ao = 0.f;
    #pragma unroll 8
    for (int kk = 0; kk < 96; ++kk){
      int k = ks*96 + kk;
      float a = A_s[k];
      float4 b = *(const float4*)(bp + (size_t)k*512);
      ai += a*b.x; af += a*b.y; ag += a*b.z; ao += a*b.w;
    }
    *(float4*)&part4[ks][d][0] = make_float4(ai, af, ag, ao);
  }
  __syncthreads();
  if (t < D2){
    float4 p0 = *(const float4*)&part4[0][t][0];
    float4 p1 = *(const float4*)&part4[1][t][0];
    float4 p2 = *(const float4*)&part4[2][t][0];
    float4 p3 = *(const float4*)&part4[3][t][0];
    float iv = p0.x+p1.x+p2.x+p3.x + lbih[t]       + lbhh[t];
    float fv = p0.y+p1.y+p2.y+p3.y + lbih[128 + t] + lbhh[128 + t];
    float gv = p0.z+p1.z+p2.z+p3.z + lbih[256 + t] + lbhh[256 + t];
    float ov = p0.w+p1.w+p2.w+p3.w + lbih[384 + t] + lbhh[384 + t];
    float c = sigmoidf_(fv)*cl[(size_t)g*D2 + t] + sigmoidf_(iv)*tanhf(gv);
    float hn = sigmoidf_(ov)*tanhf(c);
    cl[(size_t)g*D2 + t] = c;
    hl[(size_t)g*D2 + t] = hn;
    q_s[t] = hn;
  }
  __syncthreads();
  int n0 = (g*N_NODES + N_GRAPHS - 1)/N_GRAPHS;
  int n1 = ((g+1)*N_NODES + N_GRAPHS - 1)/N_GRAPHS;
  int cnt = n1 - n0;
  float e = -1e30f;
  if (t < cnt){
    int n = n0 + t;
    const float4* xr = (const float4*)(x0 + (size_t)n*H);
    const float4* hr = (const float4*)(h  + (size_t)n*H);
    const float4* q1 = (const float4*)q_s;
    const float4* q2 = (const float4*)(q_s + H);
    float s = 0.0f;
    #pragma unroll
    for (int k4 = 0; k4 < 16; ++k4){
      float4 a = xr[k4], b = q1[k4];
      s += a.x*b.x + a.y*b.y + a.z*b.z + a.w*b.w;
    }
    #pragma unroll
    for (int k4 = 0; k4 < 16; ++k4){
      float4 a = hr[k4], b = q2[k4];
      s += a.x*b.x + a.y*b.y + a.z*b.z + a.w*b.w;
    }
    e = s;
  }
  float mx = e;
  #pragma unroll
  for (int off = 32; off >= 1; off >>= 1) mx = fmaxf(mx, __shfl_xor(mx, off));
  if (lane == 0) wred[w] = mx;
  __syncthreads();
  float gm = wred[0];
  #pragma unroll
  for (int i = 1; i < 8; ++i) gm = fmaxf(gm, wred[i]);
  __syncthreads();
  float ex = (t < cnt) ? expf(e - gm) : 0.0f;
  float sm = ex;
  #pragma unroll
  for (int off = 32; off >= 1; off >>= 1) sm += __shfl_xor(sm, off);
  if (lane == 0) wred[w] = sm;
  __syncthreads();
  float denom = wred[0]+wred[1]+wred[2]+wred[3]+wred[4]+wred[5]+wred[6]+wred[7];
  if (t < cnt) alpha_s[t] = ex / denom;
  __syncthreads();
  float acc0 = 0.f, acc1 = 0.f;
  for (int i = w; i < cnt; i += 8){
    float a = alpha_s[i];
    acc0 += a * x0[(size_t)(n0+i)*H + lane];
    acc1 += a * h [(size_t)(n0+i)*H + lane];
  }
  part[w][lane]      = acc0;
  part[w][64 + lane] = acc1;
  __syncthreads();
  if (t < D2){
    float v = 0.f;
    #pragma unroll
    for (int i = 0; i < 8; ++i) v += part[i][t];
    qstar[(size_t)g*QS + t]      = q_s[t];
    qstar[(size_t)g*QS + D2 + t] = v;
  }
}

// ==================== readout (coalesced, transposed weights) ====================
__global__ __launch_bounds__(256) void out_kernel(
    const float* __restrict__ qstar, const float* __restrict__ bsp,
    const float* __restrict__ prelu, float* __restrict__ out){
  __shared__ float q_s[QS];
  int g = blockIdx.x >> 1, half = blockIdx.x & 1;
  int t = threadIdx.x;
  q_s[t] = qstar[(size_t)g*QS + t];
  __syncthreads();
  int j0 = half*512 + t;
  float acc0 = bsp[j0], acc1 = bsp[j0 + 256];
  const float* wp = d_wspT + j0;
  #pragma unroll 4
  for (int k = 0; k < QS; ++k){
    float q = q_s[k];
    acc0 += q * wp[(size_t)k*1024];
    acc1 += q * wp[(size_t)k*1024 + 256];
  }
  float pw = prelu[0];
  out[(size_t)g*READOUT + j0]       = (acc0 >= 0.0f) ? acc0 : pw*acc0;
  out[(size_t)g*READOUT + j0 + 256] = (acc1 >= 0.0f) ? acc1 : pw*acc1;
}

extern "C" void kernel_launch(void* const* d_in, const int* in_sizes, int n_in,
                              void* d_out, int out_size, void* d_ws, size_t ws_size,
                              hipStream_t stream) {
  const float* node_feats = (const float*)d_in[0];
  const float* edge_feats = (const float*)d_in[1];
  const int*   esrc       = (const int*)d_in[2];
  const int*   edst       = (const int*)d_in[3];
  const float* Wproj = (const float*)d_in[5];
  const float* bproj = (const float*)d_in[6];
  const float* Wedge = (const float*)d_in[7];
  const float* bedge = (const float*)d_in[8];
  const float* bconv = (const float*)d_in[9];
  const float* gWih  = (const float*)d_in[10];
  const float* gWhh  = (const float*)d_in[11];
  const float* gbih  = (const float*)d_in[12];
  const float* gbhh  = (const float*)d_in[13];
  const float* lWih  = (const float*)d_in[14];
  const float* lWhh  = (const float*)d_in[15];
  const float* lbih  = (const float*)d_in[16];
  const float* lbhh  = (const float*)d_in[17];
  const float* Wsp   = (const float*)d_in[18];
  const float* bsp   = (const float*)d_in[19];
  const float* prelu = (const float*)d_in[20];

  float* ws    = (float*)d_ws;
  float* x0    = ws;                     // 2,560,000
  float* h     = ws + 2560000;           // 2,560,000
  float* agg   = ws + 5120000;           // 2,560,000
  float* qstar = ws + 7680000;           // 65,536
  float* hl    = qstar + 65536;          // 32,768
  float* cl    = hl + 32768;             // 32,768
  float* Bl2   = agg;                    // s2s phase reuses dead agg (196,608)

  hipMemsetAsync(qstar, 0, (65536 + 32768 + 32768)*sizeof(float), stream);

  pack_weF<<<272, 256, 0, stream>>>(Wedge, bedge);
  pack_bcF<<<128, 256, 0, stream>>>(gWih, gWhh);
  pack_wspT<<<1024, 256, 0, stream>>>(Wsp);

  proj_mm<<<N_NODES/64, 256, 0, stream>>>(node_feats, Wproj, bproj, x0, h);

  for (int s = 0; s < 3; ++s){
    if (s == 0)
      zero_buf<<<2048, 256, 0, stream>>>((float4*)agg, N_NODES*H/4);
    edge_mfma<<<N_EDGES/64, 256, 0, stream>>>(h, edge_feats, esrc, edst, agg);
    gru_mm_mfma<<<N_NODES/64, 256, 0, stream>>>(agg, bconv, h, gbih, gbhh);  // zeroes agg
  }

  build_bl2<<<768, 256, 0, stream>>>(lWih, lWhh, Bl2);

  for (int s = 0; s < 3; ++s){
    s2s_kernel<<<N_GRAPHS, 512, 0, stream>>>(x0, h, Bl2, lbih, lbhh, hl, cl, qstar);
  }

  out_kernel<<<2*N_GRAPHS, 256, 0, stream>>>(qstar, bsp, prelu, (float*)d_out);
}